// Round 9
// baseline (253.438 us; speedup 1.0000x reference)
//
#include <hip/hip_runtime.h>
#include <hip/hip_bf16.h>

// Problem constants (B=1). All inputs/outputs are float32.
#define HH   96
#define WW   96
#define NPIX 9216          // 96*96
#define CH   128
#define NH   8
#define HD   16
#define KS   8

#define NEPIX   2304       // 48*48 even-even grid (k/v only ever read there)
#define QTP  136           // conv q-tile pitch (ch)
#define KVTP 264           // conv kv-tile pitch (k 0..127, v 128..255, pad)
#define XP2  61            // conv input-slab pitch (floats/ch: 3 rows x 20 + 1)
#define PP3  136           // attn P-lds pitch/px (ush): hi 0..63, lo 68..131
#define AOP  20            // fused attn-out LDS pitch (floats, 16B aligned)

#define MAGIC 0x1B7E9A3Du  // 4 distinct bytes: never equals a repeated-byte
                           // poison pattern; ws re-poison resets flags/iter

typedef __attribute__((ext_vector_type(8))) short bf16x8;
typedef __attribute__((ext_vector_type(4))) float f32x4;

__device__ __forceinline__ unsigned short f2bf(float f) {
    __hip_bfloat16 b = __float2bfloat16(f);
    union { __hip_bfloat16 b; unsigned short u; } cv; cv.b = b; return cv.u;
}
__device__ __forceinline__ bf16x8 u4_as_bf(uint4 u) {
    union { uint4 u; bf16x8 b; } cv; cv.u = u; return cv.b;
}

// ---------------------------------------------------------------------------
// Single fused kernel: conv (all 768 strips) + flags + attn+proj (576 segs).
// Block b: conv strip b; blocks 384..575 also conv strip b+192 (-> 576..767).
// Conv ALWAYS precedes any spin within a block => every scheduled block makes
// unconditional conv progress => all flags eventually set => deadlock-free
// with NO dispatch-order or co-residency assumption (guide G16 compliant:
// cross-block data handoff uses agent-scope release/acquire atomics).
// LDS: conv {ldsx 31232 + qt 3264 + kvt 3168 = 37.7KB} and attn {plds 34816
// + ao 10240 = 45KB} aliased in one 45KB buffer -> 3 blocks/CU.
// Conv body = R6-proven (direct weight loads, R5-proven-equal); attnproj
// body = R8-proven. Math bit-identical to R8.
// ---------------------------------------------------------------------------
__global__ __launch_bounds__(512) void fused_kernel(
    const float* __restrict__ x,        // [128][96][96]
    const float* __restrict__ w,        // [384][1][3][3]
    const float* __restrict__ bias,     // [384]
    const float* __restrict__ pw,       // [128][128] ([o][c])
    const float* __restrict__ pb,       // [128]
    unsigned short* __restrict__ q_pm,  // [NH][NPIX][16] bf16
    unsigned short* __restrict__ k_pm,  // [NH][NEPIX][16] bf16
    unsigned short* __restrict__ vt_f,  // [8][48][7][16][8] bf16
    unsigned int*   __restrict__ flags, // [768]
    float* __restrict__ out)            // [128][NPIX]
{
    __shared__ __align__(16) unsigned char smem[45056];
    // conv-phase aliases
    float*          ldsx = (float*)smem;                        // 31,232 B
    unsigned short* qt   = (unsigned short*)(smem + 31232);     //  3,264 B
    unsigned short* kvt  = (unsigned short*)(smem + 34496);     //  3,168 B
    // attn-phase aliases
    unsigned short* plds = (unsigned short*)smem;               // 34,816 B
    float*          ao   = (float*)(smem + 34816);              // 10,240 B

    const int b   = blockIdx.x;         // 0..575
    const int tid = threadIdx.x;        // 0..511

    // =================== PHASE 1: conv strips ===================
    const int nstrip = (b >= 384) ? 2 : 1;
    for (int sidx = 0; sidx < nstrip; ++sidx) {
        const int strip = (sidx == 0) ? b : b + 192;    // 0..767
        const int row = strip >> 3;     // 0..95
        const int q8  = strip & 7;      // 0..7
        const int j0q = q8 * 12;
        const bool kvrow = (row & 1) == 0;

        if (tid < 256) {
            // ---- stage x[c][row-1..row+1][j0q-4..j0q+15] (1920 f4) ----
            #pragma unroll
            for (int it = 0; it < 8; ++it) {
                const int t = it * 256 + tid;
                if (t < 1920) {
                    const int r   = t / 640;
                    const int rem = t - r * 640;
                    const int c   = rem / 5;
                    const int s4  = rem - c * 5;        // 0..4
                    const int rg  = row + r - 1;
                    const int jj  = j0q - 4 + s4 * 4;
                    float4 v = make_float4(0.f, 0.f, 0.f, 0.f);
                    if (rg >= 0 && rg < HH && jj >= 0 && jj < WW)
                        v = *(const float4*)(x + (size_t)c * NPIX + rg * WW + jj);
                    *(float4*)&ldsx[c * XP2 + r * 20 + s4 * 4] = v;
                }
            }
        }
        __syncthreads();

        if (tid < 256) {
            const int g  = tid >> 1;    // channel / group
            const int sh = tid & 1;     // 0/1 -> 6 px each
            float xr[3][8];
            {
                const float* xg_l = &ldsx[g * XP2 + 3 + sh * 6];
                #pragma unroll
                for (int dr = 0; dr < 3; ++dr)
                    #pragma unroll
                    for (int m = 0; m < 8; ++m)
                        xr[dr][m] = xg_l[dr * 20 + m];
            }
            #pragma unroll
            for (int dt = 0; dt < 3; ++dt) {
                const int o = 3 * g + dt;
                const int t = o >> 7;           // 0=q, 1=k, 2=v
                const int c = o & 127;
                float w9[9];
                #pragma unroll
                for (int k = 0; k < 9; ++k) w9[k] = w[o * 9 + k];
                const float bb = bias[o];

                if (t == 0) {
                    #pragma unroll
                    for (int px = 0; px < 6; ++px) {
                        float acc = bb;
                        #pragma unroll
                        for (int kh = 0; kh < 3; ++kh)
                            #pragma unroll
                            for (int kw = 0; kw < 3; ++kw)
                                acc += xr[kh][px + kw] * w9[kh * 3 + kw];
                        qt[(sh * 6 + px) * QTP + c] = f2bf(acc);
                    }
                } else if (kvrow) {
                    #pragma unroll
                    for (int pe = 0; pe < 3; ++pe) {
                        const int px = pe * 2;
                        float acc = bb;
                        #pragma unroll
                        for (int kh = 0; kh < 3; ++kh)
                            #pragma unroll
                            for (int kw = 0; kw < 3; ++kw)
                                acc += xr[kh][px + kw] * w9[kh * 3 + kw];
                        kvt[(sh * 3 + pe) * KVTP + (t - 1) * CH + c] = f2bf(acc);
                    }
                }
            }
        }
        __syncthreads();

        if (tid < 256) {
            const int er = row >> 1;
            const int b6 = j0q >> 1;
            const int ntask = kvrow ? ((q8 == 0) ? 800 : 672) : 192;
            #pragma unroll
            for (int it = 0; it < 4; ++it) {
                const int idx = it * 256 + tid;
                if (idx < 192) {                        // q: head-split
                    const int px = idx >> 4;
                    const int c8 = (idx & 15) * 8;
                    const int hh = c8 >> 4;
                    const int d8 = c8 & 15;
                    const uint4 v = *(const uint4*)&qt[px * QTP + c8];
                    *(uint4*)(q_pm + ((size_t)hh * NPIX + row * WW + j0q + px) * 16
                              + d8) = v;
                } else if (idx < 288 && kvrow) {        // K: head-split
                    const int k2  = idx - 192;
                    const int epx = k2 >> 4;
                    const int c8  = (k2 & 15) * 8;
                    const int hh  = c8 >> 4;
                    const int d8  = c8 & 15;
                    const uint4 v = *(const uint4*)&kvt[epx * KVTP + c8];
                    *(uint4*)(k_pm + ((size_t)hh * NEPIX + er * 48 + b6 + epx) * 16
                              + d8) = v;
                } else if (idx < 672 && kvrow) {        // V fragment tiles
                    const int v2 = idx - 288;
                    const int pr = v2 >> 7;
                    const int c  = v2 & 127;
                    const int colA  = b6 + pr * 2;
                    const int chunk = colA >> 3;
                    const int off   = colA & 7;
                    const unsigned int a0 =
                        (unsigned int)kvt[(pr * 2)     * KVTP + CH + c]
                        | ((unsigned int)kvt[(pr * 2 + 1) * KVTP + CH + c] << 16);
                    *(unsigned int*)(vt_f
                        + (((size_t)(c >> 4) * 48 + er) * 7 + chunk) * 128
                        + (c & 15) * 8 + off) = a0;
                } else if (idx < ntask) {               // zfill chunk 6
                    const int zf = idx - 672;
                    const int hh = zf >> 4;
                    const int d  = zf & 15;
                    *(uint4*)(vt_f + (((size_t)hh * 48 + er) * 7 + 6) * 128 + d * 8)
                        = make_uint4(0u, 0u, 0u, 0u);
                }
            }
        }
        __syncthreads();    // drains all threads' global writes (vmcnt 0)
        if (tid == 0)
            __hip_atomic_store(&flags[strip], MAGIC,
                               __ATOMIC_RELEASE, __HIP_MEMORY_SCOPE_AGENT);
    }

    // =================== PHASE 2: attn + proj (seg = b) ===================
    const int seg = b;                          // 0..575
    const int i   = seg / 6;                    // image row
    const int j0  = (seg - i * 6) * 16;
    const int er0 = min(max(i / 2 - 3, 0), 40);
    const int ec0 = min(max(j0 / 2 - 3, 0), 40);
    const int ecs = ec0 >> 3;
    const int sh5 = ec0 & 7;

    // ---- dependency poll: 9 rows x 8 strip-cols (q row + 8 kv rows) ----
    if (tid < 72) {
        const int rw = (tid < 64) ? 2 * (er0 + (tid >> 3)) : i;
        const unsigned fi = rw * 8 + (tid & 7);
        while (__hip_atomic_load(&flags[fi],
                   __ATOMIC_ACQUIRE, __HIP_MEMORY_SCOPE_AGENT) != MAGIC)
            __builtin_amdgcn_s_sleep(8);
    }
    __syncthreads();
    __threadfence();        // invalidate stale L1/L2 lines before data reads

    const int h    = tid >> 6;                  // head = wave
    const int lane = tid & 63;
    const int nn   = lane & 15;
    const int g    = lane >> 4;
    const int g4   = g * 4;

    const int j   = j0 + nn;
    const int ci0 = min(max(j / 2 - 3, 0), 40) - ec0;   // 0..7 (per px)

    // ---- QK^T: 8x mfma_16x16x32, A=K window row, B=Q ----
    bf16x8 qf = (bf16x8)(short)0;
    if (g < 2)
        qf = u4_as_bf(*(const uint4*)(q_pm
                + ((size_t)h * NPIX + seg * 16 + nn) * 16 + g * 8));
    const f32x4 zacc = {0.f, 0.f, 0.f, 0.f};
    f32x4 st[8];
    #pragma unroll
    for (int t = 0; t < 8; ++t) {
        bf16x8 kf = (bf16x8)(short)0;
        if (g < 2) {
            const int ep = (er0 + t) * 48 + min(ec0 + nn, 47);
            kf = u4_as_bf(*(const uint4*)(k_pm
                    + ((size_t)h * NEPIX + ep) * 16 + g * 8));
        }
        st[t] = __builtin_amdgcn_mfma_f32_16x16x32_bf16(kf, qf, zacc, 0, 0, 0);
    }

    // ---- masked softmax ----
    float m = -1e30f;
    #pragma unroll
    for (int t = 0; t < 8; ++t)
        #pragma unroll
        for (int r = 0; r < 4; ++r) {
            const int cc = g4 + r;
            float T = st[t][r] * 0.25f;
            T = ((unsigned)(cc - ci0) < 8u) ? T : -1e30f;
            st[t][r] = T;
            m = fmaxf(m, T);
        }
    m = fmaxf(m, __shfl_xor(m, 16));
    m = fmaxf(m, __shfl_xor(m, 32));

    float s = 0.f;
    #pragma unroll
    for (int t = 0; t < 8; ++t)
        #pragma unroll
        for (int r = 0; r < 4; ++r) {
            const float p = __expf(st[t][r] - m);
            st[t][r] = p;
            s += p;
        }
    s += __shfl_xor(s, 16);
    s += __shfl_xor(s, 32);

    // ---- PV in two 4-row halves; hi+lo packed to disjoint slots ----
    unsigned short* pr = plds + h * (16 * PP3) + nn * PP3;
    f32x4 acc = {0.f, 0.f, 0.f, 0.f};

    #pragma unroll
    for (int hf = 0; hf < 2; ++hf) {
        #pragma unroll
        for (int tl = 0; tl < 4; ++tl) {
            const f32x4 P = st[hf * 4 + tl];
            unsigned short hi[4], lo[4];
            #pragma unroll
            for (int r = 0; r < 4; ++r) {
                hi[r] = f2bf(P[r]);
                lo[r] = f2bf(P[r] - __uint_as_float((unsigned)hi[r] << 16));
            }
            *(uint2*)&pr[tl * 16 + g4] =
                make_uint2((unsigned)hi[0] | ((unsigned)hi[1] << 16),
                           (unsigned)hi[2] | ((unsigned)hi[3] << 16));
            *(uint2*)&pr[68 + tl * 16 + g4] =
                make_uint2((unsigned)lo[0] | ((unsigned)lo[1] << 16),
                           (unsigned)lo[2] | ((unsigned)lo[3] << 16));
        }
        #pragma unroll
        for (int ks = 0; ks < 2; ++ks) {
            const int tl = ks * 2 + (g >> 1);
            const int er = er0 + hf * 4 + tl;
            const int ch = ecs + (g & 1);
            const unsigned short* vb = vt_f
                + ((size_t)(h * 48 + er) * 7 + ch) * 128 + nn * 8;
            const uint4 u0 = *(const uint4*)vb;
            bf16x8 vf;
            if (sh5 == 0) {
                vf = u4_as_bf(u0);
            } else {                    // shift by 5 bf16 elems
                const uint4 u1 = *(const uint4*)(vb + 128);
                uint4 o;
                o.x = (u0.z >> 16) | (u0.w << 16);
                o.y = (u0.w >> 16) | (u1.x << 16);
                o.z = (u1.x >> 16) | (u1.y << 16);
                o.w = (u1.y >> 16) | (u1.z << 16);
                vf = u4_as_bf(o);
            }
            const bf16x8 ph =
                u4_as_bf(*(const uint4*)&pr[tl * 16 + (g & 1) * 8]);
            const bf16x8 po =
                u4_as_bf(*(const uint4*)&pr[68 + tl * 16 + (g & 1) * 8]);
            acc = __builtin_amdgcn_mfma_f32_16x16x32_bf16(vf, ph, acc, 0, 0, 0);
            acc = __builtin_amdgcn_mfma_f32_16x16x32_bf16(vf, po, acc, 0, 0, 0);
        }
    }

    // ---- attn epilogue -> LDS ao[128 ch][16 px] ----
    const float inv = 1.f / s;
    #pragma unroll
    for (int r = 0; r < 4; ++r)
        ao[(h * HD + g4 + r) * AOP + nn] = acc[r] * inv;

    __syncthreads();

    // ---- proj: 1 out-ch x 4 px per thread, fp32 ----
    const int o  = tid >> 2;                // 0..127
    const int p0 = (tid & 3) * 4;           // 0,4,8,12
    const float bb = pb[o];
    float ac[4] = {bb, bb, bb, bb};

    #pragma unroll 4
    for (int c0 = 0; c0 < CH; c0 += 4) {
        const float4 wv = *(const float4*)(pw + (size_t)o * CH + c0);
        const float4 a0 = *(const float4*)&ao[(c0 + 0) * AOP + p0];
        const float4 a1 = *(const float4*)&ao[(c0 + 1) * AOP + p0];
        const float4 a2 = *(const float4*)&ao[(c0 + 2) * AOP + p0];
        const float4 a3 = *(const float4*)&ao[(c0 + 3) * AOP + p0];
        ac[0] += wv.x * a0.x + wv.y * a1.x + wv.z * a2.x + wv.w * a3.x;
        ac[1] += wv.x * a0.y + wv.y * a1.y + wv.z * a2.y + wv.w * a3.y;
        ac[2] += wv.x * a0.z + wv.y * a1.z + wv.z * a2.z + wv.w * a3.z;
        ac[3] += wv.x * a0.w + wv.y * a1.w + wv.z * a2.w + wv.w * a3.w;
    }

    *(float4*)(out + (size_t)o * NPIX + seg * 16 + p0)
        = make_float4(ac[0], ac[1], ac[2], ac[3]);
}

// ---------------------------------------------------------------------------
extern "C" void kernel_launch(void* const* d_in, const int* in_sizes, int n_in,
                              void* d_out, int out_size, void* d_ws, size_t ws_size,
                              hipStream_t stream)
{
    const float* x      = (const float*)d_in[0];
    const float* qkv_w  = (const float*)d_in[1];
    const float* qkv_b  = (const float*)d_in[2];
    const float* proj_w = (const float*)d_in[3];
    const float* proj_b = (const float*)d_in[4];
    float* out = (float*)d_out;

    // ws: [q_pm 2.36 MB][k_pm 0.59 MB][vt_f 0.69 MB][flags 3 KB]
    unsigned short* q_pm = (unsigned short*)d_ws;              // [NH][NPIX][16]
    unsigned short* k_pm = q_pm + (size_t)NH * NPIX * 16;      // [NH][NEPIX][16]
    unsigned short* vt_f = k_pm + (size_t)NH * NEPIX * 16;     // [8][48][7][16][8]
    unsigned int*   flags = (unsigned int*)(vt_f + (size_t)8 * 48 * 7 * 128);

    fused_kernel<<<576, 512, 0, stream>>>(x, qkv_w, qkv_b, proj_w, proj_b,
                                          q_pm, k_pm, vt_f, flags, out);
}

// Round 10
// 87.917 us; speedup vs baseline: 2.8827x; 2.8827x over previous
//
#include <hip/hip_runtime.h>
#include <hip/hip_bf16.h>

// Problem constants (B=1). All inputs/outputs are float32.
#define HH   96
#define WW   96
#define NPIX 9216          // 96*96
#define CH   128
#define NH   8
#define HD   16
#define KS   8

#define NEPIX   2304       // 48*48 even-even grid (k/v only ever read there)
#define QTP  136           // conv q-tile pitch (ch)
#define KVTP 264           // conv kv-tile pitch (k 0..127, v 128..255, pad)
#define XP2  61            // conv input-slab pitch (floats/ch: 3 rows x 20 + 1)
#define PP3  136           // attn P-lds pitch/px (ush): hi 0..63, lo 68..131
#define AOP  20            // fused attn-out LDS pitch (floats, 16B aligned)

typedef __attribute__((ext_vector_type(8))) short bf16x8;
typedef __attribute__((ext_vector_type(4))) float f32x4;

__device__ __forceinline__ unsigned short f2bf(float f) {
    __hip_bfloat16 b = __float2bfloat16(f);
    union { __hip_bfloat16 b; unsigned short u; } cv; cv.b = b; return cv.u;
}
__device__ __forceinline__ bf16x8 u4_as_bf(uint4 u) {
    union { uint4 u; bf16x8 b; } cv; cv.u = u; return cv.b;
}

// ---------------------------------------------------------------------------
// K1: depthwise 3x3 conv (R6 body; ~5 us measured via R7 amplification).
// q -> q_pm [NH][NPIX][16]; k -> k_pm [NH][NEPIX][16];
// v -> vt_f [8][48][7][16][8] MFMA tiles (chunk 6 zero-filled).
// NOTE (R9 lesson): do NOT split this into producer/consumer flag sync with
// the attn kernel — agent-scope release stores / __threadfence at strip
// granularity trigger per-block L2 writebacks on the non-coherent XCD L2s
// (measured: 199 us, VALUBusy 4.5%). The kernel-boundary barrier is cheaper.
// ---------------------------------------------------------------------------
__global__ __launch_bounds__(256) void conv_kernel(
    const float* __restrict__ x,        // [128][96][96]
    const float* __restrict__ w,        // [384][1][3][3]
    const float* __restrict__ bias,     // [384]
    unsigned short* __restrict__ q_pm,  // [NH][NPIX][16] bf16
    unsigned short* __restrict__ k_pm,  // [NH][NEPIX][16] bf16
    unsigned short* __restrict__ vt_f)  // [8][48][7][16][8] bf16
{
    __shared__ float ldsx[128 * XP2];               // 31,232 B
    __shared__ float wl[3456];                      // 13,824 B
    __shared__ float bl[384];                       //  1,536 B
    __shared__ unsigned short qt [12 * QTP];        //  3,264 B
    __shared__ unsigned short kvt[ 6 * KVTP];       //  3,168 B

    const int row = blockIdx.x >> 3;    // 0..95
    const int q8  = blockIdx.x & 7;     // 0..7
    const int j0q = q8 * 12;
    const int tid = threadIdx.x;
    const int g   = tid >> 1;           // 0..127 input channel / group
    const int sh  = tid & 1;            // 0/1 -> 6 px each
    const bool kvrow = (row & 1) == 0;  // block-uniform

    // ---- stage x (1920 f4) + weights (864 f4) + bias (96 f4) ----
    #pragma unroll
    for (int it = 0; it < 12; ++it) {
        const int t = it * 256 + tid;
        if (t < 1920) {
            const int r   = t / 640;
            const int rem = t - r * 640;
            const int c   = rem / 5;
            const int s4  = rem - c * 5;        // 0..4
            const int rg  = row + r - 1;
            const int jj  = j0q - 4 + s4 * 4;   // 4-aligned; fully in or out
            float4 v = make_float4(0.f, 0.f, 0.f, 0.f);
            if (rg >= 0 && rg < HH && jj >= 0 && jj < WW)
                v = *(const float4*)(x + (size_t)c * NPIX + rg * WW + jj);
            *(float4*)&ldsx[c * XP2 + r * 20 + s4 * 4] = v;
        } else if (t < 2784) {
            const int f = t - 1920;             // 0..863
            *(float4*)&wl[f * 4] = *(const float4*)(w + f * 4);
        } else if (t < 2880) {
            const int f = t - 2784;             // 0..95
            *(float4*)&bl[f * 4] = *(const float4*)(bias + f * 4);
        }
    }
    __syncthreads();

    // ---- per-thread window: rel col = 3 + sh*6 + m ----
    float xr[3][8];
    {
        const float* xg_l = &ldsx[g * XP2 + 3 + sh * 6];
        #pragma unroll
        for (int dr = 0; dr < 3; ++dr)
            #pragma unroll
            for (int m = 0; m < 8; ++m)
                xr[dr][m] = xg_l[dr * 20 + m];
    }

    #pragma unroll
    for (int dt = 0; dt < 3; ++dt) {
        const int o = 3 * g + dt;       // conv out-channel (group g)
        const int t = o >> 7;           // 0=q, 1=k, 2=v
        const int c = o & 127;
        float w9[9];
        #pragma unroll
        for (int k = 0; k < 9; ++k) w9[k] = wl[o * 9 + k];
        const float b = bl[o];

        if (t == 0) {
            #pragma unroll
            for (int px = 0; px < 6; ++px) {
                float acc = b;
                #pragma unroll
                for (int kh = 0; kh < 3; ++kh)
                    #pragma unroll
                    for (int kw = 0; kw < 3; ++kw)
                        acc += xr[kh][px + kw] * w9[kh * 3 + kw];
                qt[(sh * 6 + px) * QTP + c] = f2bf(acc);
            }
        } else if (kvrow) {
            #pragma unroll
            for (int pe = 0; pe < 3; ++pe) {        // even px only
                const int px = pe * 2;
                float acc = b;
                #pragma unroll
                for (int kh = 0; kh < 3; ++kh)
                    #pragma unroll
                    for (int kw = 0; kw < 3; ++kw)
                        acc += xr[kh][px + kw] * w9[kh * 3 + kw];
                kvt[(sh * 3 + pe) * KVTP + (t - 1) * CH + c] = f2bf(acc);
            }
        }
    }

    __syncthreads();

    // ---- write out: q 192 u4; kvrow adds k 96 u4 + v 384 u32 (+zfill) ----
    const int er = row >> 1;
    const int b6 = j0q >> 1;            // 0,6,12,..,42 (even)
    const int ntask = kvrow ? ((q8 == 0) ? 800 : 672) : 192;
    #pragma unroll
    for (int it = 0; it < 4; ++it) {
        const int idx = it * 256 + tid;
        if (idx < 192) {                        // q: head-split layout
            const int px = idx >> 4;            // 0..11
            const int c8 = (idx & 15) * 8;
            const int hh = c8 >> 4;             // head
            const int d8 = c8 & 15;             // 0 or 8
            const uint4 v = *(const uint4*)&qt[px * QTP + c8];
            *(uint4*)(q_pm + ((size_t)hh * NPIX + row * WW + j0q + px) * 16
                      + d8) = v;
        } else if (idx < 288 && kvrow) {        // K: head-split layout
            const int k2  = idx - 192;
            const int epx = k2 >> 4;            // 0..5
            const int c8  = (k2 & 15) * 8;
            const int hh  = c8 >> 4;
            const int d8  = c8 & 15;
            const uint4 v = *(const uint4*)&kvt[epx * KVTP + c8];
            *(uint4*)(k_pm + ((size_t)hh * NEPIX + er * 48 + b6 + epx) * 16
                      + d8) = v;
        } else if (idx < 672 && kvrow) {        // V fragment tiles: 384 u32
            const int v2 = idx - 288;           // 0..383
            const int pr = v2 >> 7;             // 0..2 (col pair)
            const int c  = v2 & 127;
            const int colA  = b6 + pr * 2;      // even -> pair in one chunk
            const int chunk = colA >> 3;
            const int off   = colA & 7;
            const unsigned int a0 =
                (unsigned int)kvt[(pr * 2)     * KVTP + CH + c]
                | ((unsigned int)kvt[(pr * 2 + 1) * KVTP + CH + c] << 16);
            *(unsigned int*)(vt_f
                + (((size_t)(c >> 4) * 48 + er) * 7 + chunk) * 128
                + (c & 15) * 8 + off) = a0;
        } else if (idx < ntask) {               // zfill chunk 6: 128 uint4
            const int zf = idx - 672;           // 0..127
            const int hh = zf >> 4;
            const int d  = zf & 15;
            *(uint4*)(vt_f + (((size_t)hh * 48 + er) * 7 + 6) * 128 + d * 8)
                = make_uint4(0u, 0u, 0u, 0u);
        }
    }
}

// ---------------------------------------------------------------------------
// K2 (FUSED): MFMA neighborhood attention + 1x1 proj (R8-proven, best=88.3us).
// attn block (seg = 16 px, 8 waves = all 8 heads) -> ao[128][20] f32 in LDS,
// ONE barrier, then 1 out-ch x 4 px per thread in fp32.
// LDS 45.1 KB -> 3 blocks/CU. Grid 576 x 512.
// ---------------------------------------------------------------------------
__global__ __launch_bounds__(512, 4) void attnproj_kernel(
    const unsigned short* __restrict__ q_pm,    // [NH][NPIX][16] bf16
    const unsigned short* __restrict__ k_pm,    // [NH][NEPIX][16] bf16
    const unsigned short* __restrict__ vt_f,    // [8][48][7][16][8] bf16
    const float* __restrict__ pw,               // [128][128] ([o][c])
    const float* __restrict__ pb,               // [128]
    float* __restrict__ out)                    // [128][NPIX]
{
    __shared__ unsigned short plds[NH][16 * PP3];   // 34,816 B
    __shared__ float ao[CH][AOP];                   // 10,240 B

    const int seg = blockIdx.x;                 // 0..575
    const int i   = seg / 6;                    // image row
    const int j0  = (seg - i * 6) * 16;
    const int er0 = min(max(i / 2 - 3, 0), 40); // compact window row base
    const int ec0 = min(max(j0 / 2 - 3, 0), 40);// compact window col base
    const int ecs = ec0 >> 3;                   // base chunk 0..4
    const int sh5 = ec0 & 7;                    // 0 or 5 (block-uniform)

    const int tid  = threadIdx.x;
    const int h    = tid >> 6;                  // head = wave
    const int lane = tid & 63;
    const int nn   = lane & 15;                 // px (B/D cols) / d (A rows)
    const int g    = lane >> 4;                 // 0..3
    const int g4   = g * 4;

    const int j   = j0 + nn;
    const int ci0 = min(max(j / 2 - 3, 0), 40) - ec0;   // 0..7 (per px)

    // ---- QK^T: 8x mfma_16x16x32, A=K window row, B=Q ----
    bf16x8 qf = (bf16x8)(short)0;
    if (g < 2)
        qf = u4_as_bf(*(const uint4*)(q_pm
                + ((size_t)h * NPIX + seg * 16 + nn) * 16 + g * 8));
    const f32x4 zacc = {0.f, 0.f, 0.f, 0.f};
    f32x4 st[8];
    #pragma unroll
    for (int t = 0; t < 8; ++t) {
        bf16x8 kf = (bf16x8)(short)0;
        if (g < 2) {
            const int ep = (er0 + t) * 48 + min(ec0 + nn, 47);
            kf = u4_as_bf(*(const uint4*)(k_pm
                    + ((size_t)h * NEPIX + ep) * 16 + g * 8));
        }
        st[t] = __builtin_amdgcn_mfma_f32_16x16x32_bf16(kf, qf, zacc, 0, 0, 0);
    }

    // ---- masked softmax (scale 0.25 = HD^-0.5; invalid cc -> -1e30) ----
    float m = -1e30f;
    #pragma unroll
    for (int t = 0; t < 8; ++t)
        #pragma unroll
        for (int r = 0; r < 4; ++r) {
            const int cc = g4 + r;
            float T = st[t][r] * 0.25f;
            T = ((unsigned)(cc - ci0) < 8u) ? T : -1e30f;
            st[t][r] = T;
            m = fmaxf(m, T);
        }
    m = fmaxf(m, __shfl_xor(m, 16));
    m = fmaxf(m, __shfl_xor(m, 32));

    float s = 0.f;
    #pragma unroll
    for (int t = 0; t < 8; ++t)
        #pragma unroll
        for (int r = 0; r < 4; ++r) {
            const float p = __expf(st[t][r] - m);       // invalid -> 0
            st[t][r] = p;
            s += p;
        }
    s += __shfl_xor(s, 16);
    s += __shfl_xor(s, 32);

    // ---- PV in two 4-row halves; hi+lo packed to disjoint slots ----
    unsigned short* pr = &plds[h][nn * PP3];
    f32x4 acc = {0.f, 0.f, 0.f, 0.f};

    #pragma unroll
    for (int hf = 0; hf < 2; ++hf) {
        // pack P hi (slots 0..63) + lo (slots 68..131) for 4 window rows
        #pragma unroll
        for (int tl = 0; tl < 4; ++tl) {
            const f32x4 P = st[hf * 4 + tl];
            unsigned short hi[4], lo[4];
            #pragma unroll
            for (int r = 0; r < 4; ++r) {
                hi[r] = f2bf(P[r]);
                lo[r] = f2bf(P[r] - __uint_as_float((unsigned)hi[r] << 16));
            }
            *(uint2*)&pr[tl * 16 + g4] =
                make_uint2((unsigned)hi[0] | ((unsigned)hi[1] << 16),
                           (unsigned)hi[2] | ((unsigned)hi[3] << 16));
            *(uint2*)&pr[68 + tl * 16 + g4] =
                make_uint2((unsigned)lo[0] | ((unsigned)lo[1] << 16),
                           (unsigned)lo[2] | ((unsigned)lo[3] << 16));
        }
        // V frags + 4 mfma (hi, lo per ks)
        #pragma unroll
        for (int ks = 0; ks < 2; ++ks) {
            const int tl = ks * 2 + (g >> 1);
            const int er = er0 + hf * 4 + tl;
            const int ch = ecs + (g & 1);
            const unsigned short* vb = vt_f
                + ((size_t)(h * 48 + er) * 7 + ch) * 128 + nn * 8;
            const uint4 u0 = *(const uint4*)vb;
            bf16x8 vf;
            if (sh5 == 0) {
                vf = u4_as_bf(u0);
            } else {                    // shift by 5 bf16 elems
                const uint4 u1 = *(const uint4*)(vb + 128);
                uint4 o;
                o.x = (u0.z >> 16) | (u0.w << 16);
                o.y = (u0.w >> 16) | (u1.x << 16);
                o.z = (u1.x >> 16) | (u1.y << 16);
                o.w = (u1.y >> 16) | (u1.z << 16);
                vf = u4_as_bf(o);
            }
            const bf16x8 ph =
                u4_as_bf(*(const uint4*)&pr[tl * 16 + (g & 1) * 8]);
            const bf16x8 po =
                u4_as_bf(*(const uint4*)&pr[68 + tl * 16 + (g & 1) * 8]);
            acc = __builtin_amdgcn_mfma_f32_16x16x32_bf16(vf, ph, acc, 0, 0, 0);
            acc = __builtin_amdgcn_mfma_f32_16x16x32_bf16(vf, po, acc, 0, 0, 0);
        }
    }

    // ---- attn epilogue -> LDS ao[128 ch][16 px] (f32, same values) ----
    const float inv = 1.f / s;
    #pragma unroll
    for (int r = 0; r < 4; ++r)
        ao[h * HD + g4 + r][nn] = acc[r] * inv;

    __syncthreads();

    // ---- proj phase: 1 out-ch x 4 px per thread, fp32 ----
    const int o  = tid >> 2;                // 0..127
    const int p0 = (tid & 3) * 4;           // 0,4,8,12
    const float b = pb[o];
    float ac[4] = {b, b, b, b};

    #pragma unroll 4
    for (int c0 = 0; c0 < CH; c0 += 4) {
        const float4 wv = *(const float4*)(pw + (size_t)o * CH + c0);
        const float4 a0 = *(const float4*)&ao[c0 + 0][p0];
        const float4 a1 = *(const float4*)&ao[c0 + 1][p0];
        const float4 a2 = *(const float4*)&ao[c0 + 2][p0];
        const float4 a3 = *(const float4*)&ao[c0 + 3][p0];
        ac[0] += wv.x * a0.x + wv.y * a1.x + wv.z * a2.x + wv.w * a3.x;
        ac[1] += wv.x * a0.y + wv.y * a1.y + wv.z * a2.y + wv.w * a3.y;
        ac[2] += wv.x * a0.z + wv.y * a1.z + wv.z * a2.z + wv.w * a3.z;
        ac[3] += wv.x * a0.w + wv.y * a1.w + wv.z * a2.w + wv.w * a3.w;
    }

    *(float4*)(out + (size_t)o * NPIX + seg * 16 + p0)
        = make_float4(ac[0], ac[1], ac[2], ac[3]);
}

// ---------------------------------------------------------------------------
extern "C" void kernel_launch(void* const* d_in, const int* in_sizes, int n_in,
                              void* d_out, int out_size, void* d_ws, size_t ws_size,
                              hipStream_t stream)
{
    const float* x      = (const float*)d_in[0];
    const float* qkv_w  = (const float*)d_in[1];
    const float* qkv_b  = (const float*)d_in[2];
    const float* proj_w = (const float*)d_in[3];
    const float* proj_b = (const float*)d_in[4];
    float* out = (float*)d_out;

    // ws: [q_pm 2.36 MB][k_pm 0.59 MB][vt_f 0.69 MB]
    unsigned short* q_pm = (unsigned short*)d_ws;              // [NH][NPIX][16]
    unsigned short* k_pm = q_pm + (size_t)NH * NPIX * 16;      // [NH][NEPIX][16]
    unsigned short* vt_f = k_pm + (size_t)NH * NEPIX * 16;     // [8][48][7][16][8]

    conv_kernel<<<768, 256, 0, stream>>>(x, qkv_w, qkv_b, q_pm, k_pm, vt_f);
    attnproj_kernel<<<576, 512, 0, stream>>>(q_pm, k_pm, vt_f,
                                             proj_w, proj_b, out);
}